// Round 4
// baseline (21282.388 us; speedup 1.0000x reference)
//
#include <hip/hip_runtime.h>
#include <hip/hip_bf16.h>
#include <stdint.h>
#include <stddef.h>

using bf16_t = __hip_bfloat16;
typedef __attribute__((ext_vector_type(8))) short short8;
typedef __attribute__((ext_vector_type(4))) float f32x4;

// async global->LDS 16B copy (wave-uniform LDS base + lane*16 dest pattern)
__device__ __forceinline__ void gload_lds16(void* lds, const void* g) {
  __builtin_amdgcn_global_load_lds(
      (const __attribute__((address_space(1))) unsigned int*)g,
      (__attribute__((address_space(3))) unsigned int*)lds,
      16, 0, 0);
}

#define WAIT_SWITCH(w)                                                    \
  switch (w) {                                                            \
    case 3: asm volatile("s_waitcnt vmcnt(12)" ::: "memory"); break;      \
    case 2: asm volatile("s_waitcnt vmcnt(8)"  ::: "memory"); break;      \
    case 1: asm volatile("s_waitcnt vmcnt(4)"  ::: "memory"); break;      \
    default: asm volatile("s_waitcnt vmcnt(0)" ::: "memory"); break;      \
  }

// ---------------------------------------------------------------------------
// gemm128_relu:  C = relu(A*B^T + bias) -> bf16.   A: MxK, B: NxK (weights).
// BM=BN=128, BK=32. 4 waves, wave tile 64x64 (MFRAG=NFRAG=4 -> 16 MFMA per
// 8 ds_read_b128). 4-buffer LDS ring, 3 tiles in flight, counted vmcnt (T4).
// Swizzle: chunk(row,s) holds slot s^((row>>1)&3)  (pre-swizzled glb source).
// Grid: 1-D, N/128=8 columns fixed (N=1024), XCD-bijective swizzle (T1).
// ---------------------------------------------------------------------------
__global__ __launch_bounds__(256, 2)
void gemm128_relu(const bf16_t* __restrict__ A, const bf16_t* __restrict__ B,
                  const float* __restrict__ bias, bf16_t* __restrict__ obf,
                  int M, int N, int K)
{
  __shared__ __align__(16) bf16_t As[4][128 * 32];
  __shared__ __align__(16) bf16_t Bs[4][128 * 32];

  const int t    = threadIdx.x;
  const int lane = t & 63;
  const int wid  = t >> 6;
  const int wm   = wid >> 1;
  const int wn   = wid & 1;

  const int nwg = gridDim.x, bid = blockIdx.x;
  const int swz = (bid & 7) * (nwg >> 3) + (bid >> 3);
  const int bx  = swz & 7;          // N/128 = 8
  const int by  = swz >> 3;
  const int bn0 = bx * 128, bm0 = by * 128;

  const bf16_t* Ag = A + (size_t)bm0 * K;
  const bf16_t* Bg = B + (size_t)bn0 * K;

  f32x4 acc[4][4] = {};

  auto stage = [&](int b, int kt) {
    const int k0 = kt * 32;
#pragma unroll
    for (int r = 0; r < 2; ++r) {
      int ch = t + r * 256, row = ch >> 2, s = ch & 3;
      int sl = s ^ ((row >> 1) & 3);
      gload_lds16(&As[b][ch * 8], Ag + (size_t)row * K + k0 + sl * 8);
    }
#pragma unroll
    for (int r = 0; r < 2; ++r) {
      int ch = t + r * 256, row = ch >> 2, s = ch & 3;
      int sl = s ^ ((row >> 1) & 3);
      gload_lds16(&Bs[b][ch * 8], Bg + (size_t)row * K + k0 + sl * 8);
    }
  };

  const int nt = K >> 5;            // 16 (K=512) or 32 (K=1024)
  stage(0, 0); stage(1, 1); stage(2, 2); stage(3, 3);

  const int ro  = lane & 15;
  const int sl0 = lane >> 4;        // k-slot of this lane's fragment

  for (int tt = 0; tt < nt; ++tt) {
    int w = nt - 1 - tt; if (w > 3) w = 3;
    WAIT_SWITCH(w)
    __builtin_amdgcn_s_barrier();
    asm volatile("" ::: "memory");

    const int c = tt & 3;
    short8 af[4], bfr[4];
#pragma unroll
    for (int mi = 0; mi < 4; ++mi) {
      int row = wm * 64 + mi * 16 + ro;
      int ch  = row * 4 + (sl0 ^ ((row >> 1) & 3));
      af[mi]  = *(const short8*)&As[c][ch * 8];
    }
#pragma unroll
    for (int ni = 0; ni < 4; ++ni) {
      int row = wn * 64 + ni * 16 + ro;
      int ch  = row * 4 + (sl0 ^ ((row >> 1) & 3));
      bfr[ni] = *(const short8*)&Bs[c][ch * 8];
    }
#pragma unroll
    for (int mi = 0; mi < 4; ++mi)
#pragma unroll
      for (int ni = 0; ni < 4; ++ni)
        acc[mi][ni] = __builtin_amdgcn_mfma_f32_16x16x32_bf16(
            af[mi], bfr[ni], acc[mi][ni], 0, 0, 0);

    asm volatile("" ::: "memory");
    __builtin_amdgcn_s_barrier();
    asm volatile("" ::: "memory");
    if (tt + 4 < nt) stage(c, tt + 4);   // buffer c just freed
  }

  const int rb = bm0 + wm * 64, cb = bn0 + wn * 64;
#pragma unroll
  for (int mi = 0; mi < 4; ++mi)
#pragma unroll
    for (int ni = 0; ni < 4; ++ni) {
      const int col = cb + ni * 16 + ro;
      const float bv = bias[col];
#pragma unroll
      for (int r = 0; r < 4; ++r) {
        const int row = rb + mi * 16 + (lane >> 4) * 4 + r;
        obf[(size_t)row * N + col] =
            __float2bfloat16(fmaxf(acc[mi][ni][r] + bv, 0.f));
      }
    }
}

// ---------------------------------------------------------------------------
// gemm64_comb: GEMM3 + fused RK combination.  BM=BN=64, BK=64, wave 32x32.
// 4-buffer ring, 3 tiles in flight (LPT=4 -> same 12/8/4/0 vmcnt ladder).
// k arrays are bf16.  z = y + ccur*k + sum c_j*k_j.
// ---------------------------------------------------------------------------
template<bool STORE_K, bool STORE_YF>
__global__ __launch_bounds__(256, 2)
void gemm64_comb(const bf16_t* __restrict__ A, const bf16_t* __restrict__ B,
                 const float* __restrict__ bias,
                 bf16_t* __restrict__ obf,
                 bf16_t* __restrict__ kout,
                 float* __restrict__ yf_out,
                 const float* __restrict__ y_in,
                 const bf16_t* __restrict__ kp0, const bf16_t* __restrict__ kp1,
                 const bf16_t* __restrict__ kp2, const bf16_t* __restrict__ kp3,
                 float c0, float c1, float c2, float c3, float ccur,
                 int M, int N, int K)
{
  __shared__ __align__(16) bf16_t As[4][64 * 64];
  __shared__ __align__(16) bf16_t Bs[4][64 * 64];

  const int t    = threadIdx.x;
  const int lane = t & 63;
  const int wid  = t >> 6;
  const int wm   = wid >> 1;
  const int wn   = wid & 1;

  const int nwg = gridDim.x, bid = blockIdx.x;
  const int swz = (bid & 7) * (nwg >> 3) + (bid >> 3);
  const int bx  = swz & 7;          // N/64 = 8
  const int by  = swz >> 3;
  const int bn0 = bx * 64, bm0 = by * 64;

  const bf16_t* Ag = A + (size_t)bm0 * K;
  const bf16_t* Bg = B + (size_t)bn0 * K;

  f32x4 acc[2][2] = {};

  auto stage = [&](int b, int kt) {
    const int k0 = kt * 64;
#pragma unroll
    for (int r = 0; r < 2; ++r) {
      int ch = t + r * 256, row = ch >> 3, s = ch & 7;
      int sl = s ^ (row & 7);
      gload_lds16(&As[b][ch * 8], Ag + (size_t)row * K + k0 + sl * 8);
    }
#pragma unroll
    for (int r = 0; r < 2; ++r) {
      int ch = t + r * 256, row = ch >> 3, s = ch & 7;
      int sl = s ^ (row & 7);
      gload_lds16(&Bs[b][ch * 8], Bg + (size_t)row * K + k0 + sl * 8);
    }
  };

  const int nt = K >> 6;            // 16 (K=1024)
  stage(0, 0); stage(1, 1); stage(2, 2); stage(3, 3);

  const int ro = lane & 15;
  const int ks = lane >> 4;

  for (int tt = 0; tt < nt; ++tt) {
    int w = nt - 1 - tt; if (w > 3) w = 3;
    WAIT_SWITCH(w)
    __builtin_amdgcn_s_barrier();
    asm volatile("" ::: "memory");

    const int c = tt & 3;
#pragma unroll
    for (int kk = 0; kk < 2; ++kk) {
      short8 af[2], bfr[2];
      const int slot = kk * 4 + ks;
#pragma unroll
      for (int mi = 0; mi < 2; ++mi) {
        int row = wm * 32 + mi * 16 + ro;
        int ch  = row * 8 + (slot ^ (row & 7));
        af[mi]  = *(const short8*)&As[c][ch * 8];
      }
#pragma unroll
      for (int ni = 0; ni < 2; ++ni) {
        int row = wn * 32 + ni * 16 + ro;
        int ch  = row * 8 + (slot ^ (row & 7));
        bfr[ni] = *(const short8*)&Bs[c][ch * 8];
      }
#pragma unroll
      for (int mi = 0; mi < 2; ++mi)
#pragma unroll
        for (int ni = 0; ni < 2; ++ni)
          acc[mi][ni] = __builtin_amdgcn_mfma_f32_16x16x32_bf16(
              af[mi], bfr[ni], acc[mi][ni], 0, 0, 0);
    }

    asm volatile("" ::: "memory");
    __builtin_amdgcn_s_barrier();
    asm volatile("" ::: "memory");
    if (tt + 4 < nt) stage(c, tt + 4);
  }

  const int rb = bm0 + wm * 32, cb = bn0 + wn * 32;
#pragma unroll
  for (int mi = 0; mi < 2; ++mi)
#pragma unroll
    for (int ni = 0; ni < 2; ++ni) {
      const int col = cb + ni * 16 + ro;
      const float bv = bias[col];
#pragma unroll
      for (int r = 0; r < 4; ++r) {
        const int row = rb + mi * 16 + (lane >> 4) * 4 + r;
        const size_t idx = (size_t)row * N + col;
        float v = acc[mi][ni][r] + bv;              // k value (fp32)
        if (STORE_K) kout[idx] = __float2bfloat16(v);
        float z = y_in[idx] + ccur * v;
        if (kp0) z += c0 * __bfloat162float(kp0[idx]);
        if (kp1) z += c1 * __bfloat162float(kp1[idx]);
        if (kp2) z += c2 * __bfloat162float(kp2[idx]);
        if (kp3) z += c3 * __bfloat162float(kp3[idx]);
        if (STORE_YF) yf_out[idx] = z;
        obf[idx] = __float2bfloat16(z);
      }
    }
}

// ---------------------------------------------------------------------------
__global__ void init_y_kernel(const float* __restrict__ x, float* __restrict__ y,
                              bf16_t* __restrict__ yb, int n) {
  int i = blockIdx.x * blockDim.x + threadIdx.x;
  if (i < n) {
    float v = x[i];
    y[i]  = v;
    yb[i] = __float2bfloat16(v);
  }
}

__global__ void f2b_kernel(const float* __restrict__ in, bf16_t* __restrict__ out, int n) {
  int i = blockIdx.x * blockDim.x + threadIdx.x;
  if (i < n) out[i] = __float2bfloat16(in[i]);
}

// ---------------------------------------------------------------------------
extern "C" void kernel_launch(void* const* d_in, const int* in_sizes, int n_in,
                              void* d_out, int out_size, void* d_ws, size_t ws_size,
                              hipStream_t stream)
{
  const float* x  = (const float*)d_in[0];
  const float* W1 = (const float*)d_in[1];
  const float* b1 = (const float*)d_in[2];
  const float* W2 = (const float*)d_in[3];
  const float* b2 = (const float*)d_in[4];
  const float* W3 = (const float*)d_in[5];
  const float* b3 = (const float*)d_in[6];

  const int data   = in_sizes[6];            // 512
  const int hidden = in_sizes[2];            // 1024
  const int batch  = in_sizes[0] / data;     // 4096

  char* ws = (char*)d_ws;
  size_t off = 0;
  auto alloc = [&](size_t bytes) -> void* {
    off = (off + 255) & ~(size_t)255;
    void* p = ws + off;
    off += bytes;
    return p;
  };
  const size_t nyd = (size_t)batch * data;
  const size_t nh  = (size_t)batch * hidden;

  float*  y   = (float*)alloc(nyd * 4);
  bf16_t* yb  = (bf16_t*)alloc(nyd * 2);
  bf16_t* zb  = (bf16_t*)alloc(nyd * 2);
  bf16_t* h1  = (bf16_t*)alloc(nh * 2);
  bf16_t* h2  = (bf16_t*)alloc(nh * 2);
  bf16_t* k1  = (bf16_t*)alloc(nyd * 2);
  bf16_t* k2  = (bf16_t*)alloc(nyd * 2);
  bf16_t* k3  = (bf16_t*)alloc(nyd * 2);
  bf16_t* k4  = (bf16_t*)alloc(nyd * 2);
  bf16_t* k5  = (bf16_t*)alloc(nyd * 2);
  bf16_t* W1b = (bf16_t*)alloc((size_t)hidden * data * 2);
  bf16_t* W2b = (bf16_t*)alloc((size_t)hidden * hidden * 2);
  bf16_t* W3b = (bf16_t*)alloc((size_t)data * hidden * 2);

  {
    int n = (int)nyd;
    init_y_kernel<<<(n + 255) / 256, 256, 0, stream>>>(x, y, yb, n);
    n = hidden * data;
    f2b_kernel<<<(n + 255) / 256, 256, 0, stream>>>(W1, W1b, n);
    n = hidden * hidden;
    f2b_kernel<<<(n + 255) / 256, 256, 0, stream>>>(W2, W2b, n);
    n = data * hidden;
    f2b_kernel<<<(n + 255) / 256, 256, 0, stream>>>(W3, W3b, n);
  }

  const double hh = 1.0 / 64.0;
  const float hA21 = (float)(hh * (1.0/5.0));
  const float hA31 = (float)(hh * (3.0/40.0)),    hA32 = (float)(hh * (9.0/40.0));
  const float hA41 = (float)(hh * (44.0/45.0)),   hA42 = (float)(hh * (-56.0/15.0)),
              hA43 = (float)(hh * (32.0/9.0));
  const float hA51 = (float)(hh * (19372.0/6561.0)),  hA52 = (float)(hh * (-25360.0/2187.0)),
              hA53 = (float)(hh * (64448.0/6561.0)),  hA54 = (float)(hh * (-212.0/729.0));
  const float hA61 = (float)(hh * (9017.0/3168.0)),   hA62 = (float)(hh * (-355.0/33.0)),
              hA63 = (float)(hh * (46732.0/5247.0)),  hA64 = (float)(hh * (49.0/176.0)),
              hA65 = (float)(hh * (-5103.0/18656.0));
  const float hB1 = (float)(hh * (35.0/384.0)),   hB3 = (float)(hh * (500.0/1113.0)),
              hB4 = (float)(hh * (125.0/192.0)),  hB5 = (float)(hh * (-2187.0/6784.0)),
              hB6 = (float)(hh * (11.0/84.0));

  const dim3 blk(256);
  const int gridH = (hidden / 128) * (batch / 128);  // 8*32 = 256 blocks
  const int grid3 = (data / 64) * (batch / 64);      // 8*64 = 512 blocks

  auto mlp_front = [&](const bf16_t* zin) {
    gemm128_relu<<<gridH, blk, 0, stream>>>(zin, W1b, b1, h1, batch, hidden, data);
    gemm128_relu<<<gridH, blk, 0, stream>>>(h1,  W2b, b2, h2, batch, hidden, hidden);
  };

  auto stage_k = [&](bf16_t* kout, const bf16_t* p0, float cc0, const bf16_t* p1, float cc1,
                     const bf16_t* p2, float cc2, const bf16_t* p3, float cc3, float ccur) {
    gemm64_comb<true, false><<<grid3, blk, 0, stream>>>(
        h2, W3b, b3, zb, kout, nullptr, y,
        p0, p1, p2, p3, cc0, cc1, cc2, cc3, ccur,
        batch, data, hidden);
  };

  for (int step = 0; step < 64; ++step) {
    mlp_front(yb);
    stage_k(k1, nullptr, 0.f, nullptr, 0.f, nullptr, 0.f, nullptr, 0.f, hA21);
    mlp_front(zb);
    stage_k(k2, k1, hA31, nullptr, 0.f, nullptr, 0.f, nullptr, 0.f, hA32);
    mlp_front(zb);
    stage_k(k3, k1, hA41, k2, hA42, nullptr, 0.f, nullptr, 0.f, hA43);
    mlp_front(zb);
    stage_k(k4, k1, hA51, k2, hA52, k3, hA53, nullptr, 0.f, hA54);
    mlp_front(zb);
    stage_k(k5, k1, hA61, k2, hA62, k3, hA63, k4, hA64, hA65);
    mlp_front(zb);
    float* yf = (step == 63) ? (float*)d_out : y;
    gemm64_comb<false, true><<<grid3, blk, 0, stream>>>(
        h2, W3b, b3, yb, nullptr, yf, y,
        k1, k3, k4, k5, hB1, hB3, hB4, hB5, hB6,
        batch, data, hidden);
  }
}

// Round 5
// 18719.315 us; speedup vs baseline: 1.1369x; 1.1369x over previous
//
#include <hip/hip_runtime.h>
#include <hip/hip_bf16.h>
#include <stdint.h>
#include <stddef.h>

using bf16_t = __hip_bfloat16;
typedef __attribute__((ext_vector_type(8))) short short8;
typedef __attribute__((ext_vector_type(4))) float f32x4;

// async global->LDS 16B copy (wave-uniform LDS base + lane*16 dest pattern)
__device__ __forceinline__ void gload_lds16(void* lds, const void* g) {
  __builtin_amdgcn_global_load_lds(
      (const __attribute__((address_space(1))) unsigned int*)g,
      (__attribute__((address_space(3))) unsigned int*)lds,
      16, 0, 0);
}

// ---------------------------------------------------------------------------
// GEMM  C[m][n] = sum_k A[m][k] * B[n][k]   (A: MxK bf16, B: NxK bf16)
// BM=32*MFRAG (128 or 64), BN=64, BK=64. 4 waves (2x2), 256 threads.
// Schedule (1 barrier / K-step, T4 counted vmcnt, stage-early):
//   [wait vmcnt(LPT)] [barrier] [stage tile t+2] [setprio-wrapped MFMA]
// 3-buffer LDS ring, depth-2 prefetch. Safety: passing the barrier of iter t
// implies all waves finished reading buf((t-1)%3) = stage target.
// LDS 16B-chunk XOR swizzle via pre-swizzled global source (rule 21).
// 1-D grid, XCD-bijective swizzle (T1): nwg % 8 == 0.
// ---------------------------------------------------------------------------
template<int MFRAG, bool RELU, bool COMBINE, bool STORE_K, bool STORE_YF>
__global__ __launch_bounds__(256, 2)
void gemm_bt(const bf16_t* __restrict__ A, const bf16_t* __restrict__ B,
             const float* __restrict__ bias,
             bf16_t* __restrict__ obf,
             bf16_t* __restrict__ kout,
             float* __restrict__ yf_out,
             const float* __restrict__ y_in,
             const bf16_t* __restrict__ kp0, const bf16_t* __restrict__ kp1,
             const bf16_t* __restrict__ kp2, const bf16_t* __restrict__ kp3,
             float c0, float c1, float c2, float c3, float ccur,
             int M, int N, int K, int lgx)
{
  constexpr int BM = 32 * MFRAG;       // 128 (MFRAG=4) or 64 (MFRAG=2)
  constexpr int BN = 64;
  constexpr int NFRAG = 2;
  constexpr int AR = BM / 32;          // A staging rounds (4 or 2)
  constexpr int BR = 2;                // B staging rounds
  constexpr int LPT = AR + BR;         // loads/thread/tile (6 or 4)

  __shared__ __align__(16) bf16_t As[3][BM * 64];
  __shared__ __align__(16) bf16_t Bs[3][BN * 64];

  const int t    = threadIdx.x;
  const int lane = t & 63;
  const int wid  = t >> 6;
  const int wm   = wid >> 1;
  const int wn   = wid & 1;

  const int nwg = gridDim.x, bid = blockIdx.x;
  const int swz = (bid & 7) * (nwg >> 3) + (bid >> 3);
  const int gxm = (1 << lgx) - 1;
  const int bx  = swz & gxm;
  const int by  = swz >> lgx;
  const int bn0 = bx * BN, bm0 = by * BM;

  const bf16_t* Ag = A + (size_t)bm0 * K;
  const bf16_t* Bg = B + (size_t)bn0 * K;

  f32x4 acc[MFRAG][NFRAG] = {};

  // stage tile kt into buffer b (chunk(row,s) holds slot s^(row&7))
  auto stage = [&](int b, int kt) {
    const int k0 = kt * 64;
#pragma unroll
    for (int r = 0; r < AR; ++r) {
      int ch  = t + r * 256;
      int row = ch >> 3, s = ch & 7;
      int sl  = s ^ (row & 7);
      gload_lds16(&As[b][ch * 8], Ag + (size_t)row * K + k0 + sl * 8);
    }
#pragma unroll
    for (int r = 0; r < BR; ++r) {
      int ch  = t + r * 256;
      int row = ch >> 3, s = ch & 7;
      int sl  = s ^ (row & 7);
      gload_lds16(&Bs[b][ch * 8], Bg + (size_t)row * K + k0 + sl * 8);
    }
  };

  const int nt = K >> 6;
  stage(0, 0);
  stage(1, 1);

  const int ro = lane & 15;
  const int ks = lane >> 4;

  int c = 0;                            // buffer holding tile tt
  for (int tt = 0; tt < nt; ++tt) {
    // retire tile tt's loads; keep tile tt+1's in flight (T4)
    if (tt == nt - 1) {
      asm volatile("s_waitcnt vmcnt(0)" ::: "memory");
    } else if constexpr (LPT == 6) {
      asm volatile("s_waitcnt vmcnt(6)" ::: "memory");
    } else {
      asm volatile("s_waitcnt vmcnt(4)" ::: "memory");
    }
    __builtin_amdgcn_s_barrier();
    asm volatile("" ::: "memory");

    // stage-early: issue next prefetch before compute (extra latency cover)
    if (tt + 2 < nt) {
      int nb = c + 2; if (nb >= 3) nb -= 3;   // buffer of tile tt-1: free now
      stage(nb, tt + 2);
    }

#pragma unroll
    for (int kk = 0; kk < 2; ++kk) {
      short8 af[MFRAG], bfr[NFRAG];
      const int slot = kk * 4 + ks;
#pragma unroll
      for (int mi = 0; mi < MFRAG; ++mi) {
        int row = wm * (MFRAG * 16) + mi * 16 + ro;
        int ch  = row * 8 + (slot ^ (row & 7));
        af[mi]  = *(const short8*)&As[c][ch * 8];
      }
#pragma unroll
      for (int ni = 0; ni < NFRAG; ++ni) {
        int row = wn * 32 + ni * 16 + ro;
        int ch  = row * 8 + (slot ^ (row & 7));
        bfr[ni] = *(const short8*)&Bs[c][ch * 8];
      }
      __builtin_amdgcn_s_setprio(1);
#pragma unroll
      for (int mi = 0; mi < MFRAG; ++mi)
#pragma unroll
        for (int ni = 0; ni < NFRAG; ++ni)
          acc[mi][ni] = __builtin_amdgcn_mfma_f32_16x16x32_bf16(
              af[mi], bfr[ni], acc[mi][ni], 0, 0, 0);
      __builtin_amdgcn_s_setprio(0);
    }

    if (++c == 3) c = 0;
  }

  // ---- epilogue -----------------------------------------------------------
  const int rb = bm0 + wm * (MFRAG * 16);
  const int cb = bn0 + wn * 32;
#pragma unroll
  for (int mi = 0; mi < MFRAG; ++mi) {
#pragma unroll
    for (int ni = 0; ni < NFRAG; ++ni) {
      const int col = cb + ni * 16 + ro;
      const float bv = bias[col];
#pragma unroll
      for (int r = 0; r < 4; ++r) {
        const int row = rb + mi * 16 + (lane >> 4) * 4 + r;
        const size_t idx = (size_t)row * N + col;
        float v = acc[mi][ni][r] + bv;
        if (RELU) v = fmaxf(v, 0.f);
        if (COMBINE) {
          if (STORE_K) kout[idx] = __float2bfloat16(v);
          float z = y_in[idx] + ccur * v;
          if (kp0) z += c0 * __bfloat162float(kp0[idx]);
          if (kp1) z += c1 * __bfloat162float(kp1[idx]);
          if (kp2) z += c2 * __bfloat162float(kp2[idx]);
          if (kp3) z += c3 * __bfloat162float(kp3[idx]);
          if (STORE_YF) yf_out[idx] = z;
          obf[idx] = __float2bfloat16(z);
        } else {
          obf[idx] = __float2bfloat16(v);
        }
      }
    }
  }
}

// ---------------------------------------------------------------------------
__global__ void init_y_kernel(const float* __restrict__ x, float* __restrict__ y,
                              bf16_t* __restrict__ yb, int n) {
  int i = blockIdx.x * blockDim.x + threadIdx.x;
  if (i < n) {
    float v = x[i];
    y[i]  = v;
    yb[i] = __float2bfloat16(v);
  }
}

__global__ void f2b_kernel(const float* __restrict__ in, bf16_t* __restrict__ out, int n) {
  int i = blockIdx.x * blockDim.x + threadIdx.x;
  if (i < n) out[i] = __float2bfloat16(in[i]);
}

// ---------------------------------------------------------------------------
extern "C" void kernel_launch(void* const* d_in, const int* in_sizes, int n_in,
                              void* d_out, int out_size, void* d_ws, size_t ws_size,
                              hipStream_t stream)
{
  const float* x  = (const float*)d_in[0];
  const float* W1 = (const float*)d_in[1];
  const float* b1 = (const float*)d_in[2];
  const float* W2 = (const float*)d_in[3];
  const float* b2 = (const float*)d_in[4];
  const float* W3 = (const float*)d_in[5];
  const float* b3 = (const float*)d_in[6];

  const int data   = in_sizes[6];            // 512
  const int hidden = in_sizes[2];            // 1024
  const int batch  = in_sizes[0] / data;     // 4096

  char* ws = (char*)d_ws;
  size_t off = 0;
  auto alloc = [&](size_t bytes) -> void* {
    off = (off + 255) & ~(size_t)255;
    void* p = ws + off;
    off += bytes;
    return p;
  };
  const size_t nyd = (size_t)batch * data;
  const size_t nh  = (size_t)batch * hidden;

  float*  y   = (float*)alloc(nyd * 4);
  bf16_t* yb  = (bf16_t*)alloc(nyd * 2);
  bf16_t* zb  = (bf16_t*)alloc(nyd * 2);
  bf16_t* h1  = (bf16_t*)alloc(nh * 2);
  bf16_t* h2  = (bf16_t*)alloc(nh * 2);
  bf16_t* k1  = (bf16_t*)alloc(nyd * 2);
  bf16_t* k2  = (bf16_t*)alloc(nyd * 2);
  bf16_t* k3  = (bf16_t*)alloc(nyd * 2);
  bf16_t* k4  = (bf16_t*)alloc(nyd * 2);
  bf16_t* k5  = (bf16_t*)alloc(nyd * 2);
  bf16_t* W1b = (bf16_t*)alloc((size_t)hidden * data * 2);
  bf16_t* W2b = (bf16_t*)alloc((size_t)hidden * hidden * 2);
  bf16_t* W3b = (bf16_t*)alloc((size_t)data * hidden * 2);

  {
    int n = (int)nyd;
    init_y_kernel<<<(n + 255) / 256, 256, 0, stream>>>(x, y, yb, n);
    n = hidden * data;
    f2b_kernel<<<(n + 255) / 256, 256, 0, stream>>>(W1, W1b, n);
    n = hidden * hidden;
    f2b_kernel<<<(n + 255) / 256, 256, 0, stream>>>(W2, W2b, n);
    n = data * hidden;
    f2b_kernel<<<(n + 255) / 256, 256, 0, stream>>>(W3, W3b, n);
  }

  const double hh = 1.0 / 64.0;
  const float hA21 = (float)(hh * (1.0/5.0));
  const float hA31 = (float)(hh * (3.0/40.0)),    hA32 = (float)(hh * (9.0/40.0));
  const float hA41 = (float)(hh * (44.0/45.0)),   hA42 = (float)(hh * (-56.0/15.0)),
              hA43 = (float)(hh * (32.0/9.0));
  const float hA51 = (float)(hh * (19372.0/6561.0)),  hA52 = (float)(hh * (-25360.0/2187.0)),
              hA53 = (float)(hh * (64448.0/6561.0)),  hA54 = (float)(hh * (-212.0/729.0));
  const float hA61 = (float)(hh * (9017.0/3168.0)),   hA62 = (float)(hh * (-355.0/33.0)),
              hA63 = (float)(hh * (46732.0/5247.0)),  hA64 = (float)(hh * (49.0/176.0)),
              hA65 = (float)(hh * (-5103.0/18656.0));
  const float hB1 = (float)(hh * (35.0/384.0)),   hB3 = (float)(hh * (500.0/1113.0)),
              hB4 = (float)(hh * (125.0/192.0)),  hB5 = (float)(hh * (-2187.0/6784.0)),
              hB6 = (float)(hh * (11.0/84.0));

  const dim3 blk(256);
  const int gridH = (hidden / 64) * (batch / 128);  // 16*32 = 512, lgx=4
  const int grid3 = (data / 64) * (batch / 64);     //  8*64 = 512, lgx=3
  const int lgxH = 4, lgx3 = 3;

  auto mlp_front = [&](const bf16_t* zin) {
    gemm_bt<4, true, false, false, false><<<gridH, blk, 0, stream>>>(
        zin, W1b, b1, h1, nullptr, nullptr, nullptr,
        nullptr, nullptr, nullptr, nullptr, 0.f, 0.f, 0.f, 0.f, 0.f,
        batch, hidden, data, lgxH);
    gemm_bt<4, true, false, false, false><<<gridH, blk, 0, stream>>>(
        h1, W2b, b2, h2, nullptr, nullptr, nullptr,
        nullptr, nullptr, nullptr, nullptr, 0.f, 0.f, 0.f, 0.f, 0.f,
        batch, hidden, hidden, lgxH);
  };

  auto stage_k = [&](bf16_t* kout, const bf16_t* p0, float cc0, const bf16_t* p1, float cc1,
                     const bf16_t* p2, float cc2, const bf16_t* p3, float cc3, float ccur) {
    gemm_bt<2, false, true, true, false><<<grid3, blk, 0, stream>>>(
        h2, W3b, b3, zb, kout, nullptr, y,
        p0, p1, p2, p3, cc0, cc1, cc2, cc3, ccur,
        batch, data, hidden, lgx3);
  };

  for (int step = 0; step < 64; ++step) {
    mlp_front(yb);
    stage_k(k1, nullptr, 0.f, nullptr, 0.f, nullptr, 0.f, nullptr, 0.f, hA21);
    mlp_front(zb);
    stage_k(k2, k1, hA31, nullptr, 0.f, nullptr, 0.f, nullptr, 0.f, hA32);
    mlp_front(zb);
    stage_k(k3, k1, hA41, k2, hA42, nullptr, 0.f, nullptr, 0.f, hA43);
    mlp_front(zb);
    stage_k(k4, k1, hA51, k2, hA52, k3, hA53, nullptr, 0.f, hA54);
    mlp_front(zb);
    stage_k(k5, k1, hA61, k2, hA62, k3, hA63, k4, hA64, hA65);
    mlp_front(zb);
    float* yf = (step == 63) ? (float*)d_out : y;
    gemm_bt<2, false, true, false, true><<<grid3, blk, 0, stream>>>(
        h2, W3b, b3, yb, nullptr, yf, y,
        k1, k3, k4, k5, hB1, hB3, hB4, hB5, hB6,
        batch, data, hidden, lgx3);
  }
}

// Round 6
// 18262.268 us; speedup vs baseline: 1.1654x; 1.0250x over previous
//
#include <hip/hip_runtime.h>
#include <hip/hip_bf16.h>
#include <stdint.h>
#include <stddef.h>

using bf16_t = __hip_bfloat16;
typedef __attribute__((ext_vector_type(8))) short short8;
typedef __attribute__((ext_vector_type(4))) float f32x4;

// async global->LDS 16B copy (wave-uniform LDS base + lane*16 dest pattern)
__device__ __forceinline__ void gload_lds16(void* lds, const void* g) {
  __builtin_amdgcn_global_load_lds(
      (const __attribute__((address_space(1))) unsigned int*)g,
      (__attribute__((address_space(3))) unsigned int*)lds,
      16, 0, 0);
}

// ---------------------------------------------------------------------------
// GEMM  C[m][n] = sum_k A[m][k] * B[n][k]   (A: MxK bf16, B: NxK bf16)
// BM=BN=64, BK=64. 4 waves (2x2), wave tile 32x32, 256 threads.
// HIGH-OCCUPANCY config: 2-buffer LDS (32 KB/block) -> 4 blocks/CU
// (16 waves/CU, 4/SIMD). T3-minimum schedule, 1 barrier per K-step:
//   [wait vmcnt(0)] [barrier] [stage tile t+1 -> other buf] [compute t]
// Depth-1 prefetch; residual load latency covered by TLP (4 waves/SIMD).
// LDS 16B-chunk XOR swizzle (slot s^(row&7)) via pre-swizzled global source.
// 1-D grid, XCD-bijective swizzle (T1): nwg % 8 == 0.
// ---------------------------------------------------------------------------
template<bool RELU, bool COMBINE, bool STORE_K, bool STORE_YF>
__global__ __launch_bounds__(256, 4)
void gemm_bt(const bf16_t* __restrict__ A, const bf16_t* __restrict__ B,
             const float* __restrict__ bias,
             bf16_t* __restrict__ obf,
             bf16_t* __restrict__ kout,
             float* __restrict__ yf_out,
             const float* __restrict__ y_in,
             const bf16_t* __restrict__ kp0, const bf16_t* __restrict__ kp1,
             const bf16_t* __restrict__ kp2, const bf16_t* __restrict__ kp3,
             float c0, float c1, float c2, float c3, float ccur,
             int M, int N, int K, int lgx)
{
  __shared__ __align__(16) bf16_t As[2][64 * 64];
  __shared__ __align__(16) bf16_t Bs[2][64 * 64];

  const int t    = threadIdx.x;
  const int lane = t & 63;
  const int wid  = t >> 6;
  const int wm   = wid >> 1;   // 0..1
  const int wn   = wid & 1;    // 0..1

  const int nwg = gridDim.x, bid = blockIdx.x;
  const int swz = (bid & 7) * (nwg >> 3) + (bid >> 3);
  const int gxm = (1 << lgx) - 1;
  const int bx  = swz & gxm;
  const int by  = swz >> lgx;
  const int bn0 = bx * 64, bm0 = by * 64;

  const bf16_t* Ag = A + (size_t)bm0 * K;
  const bf16_t* Bg = B + (size_t)bn0 * K;

  f32x4 acc[2][2] = {};

  // stage tile kt into buffer b; chunk(row,s) holds logical slot s^(row&7)
  auto stage = [&](int b, int kt) {
    const int k0 = kt * 64;
#pragma unroll
    for (int r = 0; r < 2; ++r) {           // A: 64*8=512 chunks, 2 rounds
      int ch  = t + r * 256;
      int row = ch >> 3, s = ch & 7;
      int sl  = s ^ (row & 7);
      gload_lds16(&As[b][ch * 8], Ag + (size_t)row * K + k0 + sl * 8);
    }
#pragma unroll
    for (int r = 0; r < 2; ++r) {           // B: 2 rounds
      int ch  = t + r * 256;
      int row = ch >> 3, s = ch & 7;
      int sl  = s ^ (row & 7);
      gload_lds16(&Bs[b][ch * 8], Bg + (size_t)row * K + k0 + sl * 8);
    }
  };

  const int nt = K >> 6;
  stage(0, 0);

  const int ro = lane & 15;
  const int ks = lane >> 4;

  for (int tt = 0; tt < nt; ++tt) {
    const int c = tt & 1;
    // retire tile tt's loads (only outstanding ones at this point)
    asm volatile("s_waitcnt vmcnt(0)" ::: "memory");
    __builtin_amdgcn_s_barrier();          // all waves done with buf c^1
    asm volatile("" ::: "memory");

    if (tt + 1 < nt) stage(c ^ 1, tt + 1); // issue next tile's loads early

#pragma unroll
    for (int kk = 0; kk < 2; ++kk) {
      short8 af[2], bfr[2];
      const int slot = kk * 4 + ks;
#pragma unroll
      for (int mi = 0; mi < 2; ++mi) {
        int row = wm * 32 + mi * 16 + ro;
        int ch  = row * 8 + (slot ^ (row & 7));
        af[mi]  = *(const short8*)&As[c][ch * 8];
      }
#pragma unroll
      for (int ni = 0; ni < 2; ++ni) {
        int row = wn * 32 + ni * 16 + ro;
        int ch  = row * 8 + (slot ^ (row & 7));
        bfr[ni] = *(const short8*)&Bs[c][ch * 8];
      }
      __builtin_amdgcn_s_setprio(1);
#pragma unroll
      for (int mi = 0; mi < 2; ++mi)
#pragma unroll
        for (int ni = 0; ni < 2; ++ni)
          acc[mi][ni] = __builtin_amdgcn_mfma_f32_16x16x32_bf16(
              af[mi], bfr[ni], acc[mi][ni], 0, 0, 0);
      __builtin_amdgcn_s_setprio(0);
    }
  }

  // ---- epilogue -----------------------------------------------------------
  const int rb = bm0 + wm * 32;
  const int cb = bn0 + wn * 32;
#pragma unroll
  for (int mi = 0; mi < 2; ++mi) {
#pragma unroll
    for (int ni = 0; ni < 2; ++ni) {
      const int col = cb + ni * 16 + ro;
      const float bv = bias[col];
#pragma unroll
      for (int r = 0; r < 4; ++r) {
        const int row = rb + mi * 16 + (lane >> 4) * 4 + r;
        const size_t idx = (size_t)row * N + col;
        float v = acc[mi][ni][r] + bv;
        if (RELU) v = fmaxf(v, 0.f);
        if (COMBINE) {
          if (STORE_K) kout[idx] = __float2bfloat16(v);
          float z = y_in[idx] + ccur * v;
          if (kp0) z += c0 * __bfloat162float(kp0[idx]);
          if (kp1) z += c1 * __bfloat162float(kp1[idx]);
          if (kp2) z += c2 * __bfloat162float(kp2[idx]);
          if (kp3) z += c3 * __bfloat162float(kp3[idx]);
          if (STORE_YF) yf_out[idx] = z;
          obf[idx] = __float2bfloat16(z);
        } else {
          obf[idx] = __float2bfloat16(v);
        }
      }
    }
  }
}

// ---------------------------------------------------------------------------
__global__ void init_y_kernel(const float* __restrict__ x, float* __restrict__ y,
                              bf16_t* __restrict__ yb, int n) {
  int i = blockIdx.x * blockDim.x + threadIdx.x;
  if (i < n) {
    float v = x[i];
    y[i]  = v;
    yb[i] = __float2bfloat16(v);
  }
}

__global__ void f2b_kernel(const float* __restrict__ in, bf16_t* __restrict__ out, int n) {
  int i = blockIdx.x * blockDim.x + threadIdx.x;
  if (i < n) out[i] = __float2bfloat16(in[i]);
}

// ---------------------------------------------------------------------------
extern "C" void kernel_launch(void* const* d_in, const int* in_sizes, int n_in,
                              void* d_out, int out_size, void* d_ws, size_t ws_size,
                              hipStream_t stream)
{
  const float* x  = (const float*)d_in[0];
  const float* W1 = (const float*)d_in[1];
  const float* b1 = (const float*)d_in[2];
  const float* W2 = (const float*)d_in[3];
  const float* b2 = (const float*)d_in[4];
  const float* W3 = (const float*)d_in[5];
  const float* b3 = (const float*)d_in[6];

  const int data   = in_sizes[6];            // 512
  const int hidden = in_sizes[2];            // 1024
  const int batch  = in_sizes[0] / data;     // 4096

  char* ws = (char*)d_ws;
  size_t off = 0;
  auto alloc = [&](size_t bytes) -> void* {
    off = (off + 255) & ~(size_t)255;
    void* p = ws + off;
    off += bytes;
    return p;
  };
  const size_t nyd = (size_t)batch * data;
  const size_t nh  = (size_t)batch * hidden;

  float*  y   = (float*)alloc(nyd * 4);
  bf16_t* yb  = (bf16_t*)alloc(nyd * 2);
  bf16_t* zb  = (bf16_t*)alloc(nyd * 2);
  bf16_t* h1  = (bf16_t*)alloc(nh * 2);
  bf16_t* h2  = (bf16_t*)alloc(nh * 2);
  bf16_t* k1  = (bf16_t*)alloc(nyd * 2);
  bf16_t* k2  = (bf16_t*)alloc(nyd * 2);
  bf16_t* k3  = (bf16_t*)alloc(nyd * 2);
  bf16_t* k4  = (bf16_t*)alloc(nyd * 2);
  bf16_t* k5  = (bf16_t*)alloc(nyd * 2);
  bf16_t* W1b = (bf16_t*)alloc((size_t)hidden * data * 2);
  bf16_t* W2b = (bf16_t*)alloc((size_t)hidden * hidden * 2);
  bf16_t* W3b = (bf16_t*)alloc((size_t)data * hidden * 2);

  {
    int n = (int)nyd;
    init_y_kernel<<<(n + 255) / 256, 256, 0, stream>>>(x, y, yb, n);
    n = hidden * data;
    f2b_kernel<<<(n + 255) / 256, 256, 0, stream>>>(W1, W1b, n);
    n = hidden * hidden;
    f2b_kernel<<<(n + 255) / 256, 256, 0, stream>>>(W2, W2b, n);
    n = data * hidden;
    f2b_kernel<<<(n + 255) / 256, 256, 0, stream>>>(W3, W3b, n);
  }

  const double hh = 1.0 / 64.0;
  const float hA21 = (float)(hh * (1.0/5.0));
  const float hA31 = (float)(hh * (3.0/40.0)),    hA32 = (float)(hh * (9.0/40.0));
  const float hA41 = (float)(hh * (44.0/45.0)),   hA42 = (float)(hh * (-56.0/15.0)),
              hA43 = (float)(hh * (32.0/9.0));
  const float hA51 = (float)(hh * (19372.0/6561.0)),  hA52 = (float)(hh * (-25360.0/2187.0)),
              hA53 = (float)(hh * (64448.0/6561.0)),  hA54 = (float)(hh * (-212.0/729.0));
  const float hA61 = (float)(hh * (9017.0/3168.0)),   hA62 = (float)(hh * (-355.0/33.0)),
              hA63 = (float)(hh * (46732.0/5247.0)),  hA64 = (float)(hh * (49.0/176.0)),
              hA65 = (float)(hh * (-5103.0/18656.0));
  const float hB1 = (float)(hh * (35.0/384.0)),   hB3 = (float)(hh * (500.0/1113.0)),
              hB4 = (float)(hh * (125.0/192.0)),  hB5 = (float)(hh * (-2187.0/6784.0)),
              hB6 = (float)(hh * (11.0/84.0));

  const dim3 blk(256);
  const int gridH = (hidden / 64) * (batch / 64);   // 16*64 = 1024, lgx=4
  const int grid3 = (data / 64) * (batch / 64);     //  8*64 = 512,  lgx=3
  const int lgxH = 4, lgx3 = 3;

  auto mlp_front = [&](const bf16_t* zin) {
    gemm_bt<true, false, false, false><<<gridH, blk, 0, stream>>>(
        zin, W1b, b1, h1, nullptr, nullptr, nullptr,
        nullptr, nullptr, nullptr, nullptr, 0.f, 0.f, 0.f, 0.f, 0.f,
        batch, hidden, data, lgxH);
    gemm_bt<true, false, false, false><<<gridH, blk, 0, stream>>>(
        h1, W2b, b2, h2, nullptr, nullptr, nullptr,
        nullptr, nullptr, nullptr, nullptr, 0.f, 0.f, 0.f, 0.f, 0.f,
        batch, hidden, hidden, lgxH);
  };

  auto stage_k = [&](bf16_t* kout, const bf16_t* p0, float cc0, const bf16_t* p1, float cc1,
                     const bf16_t* p2, float cc2, const bf16_t* p3, float cc3, float ccur) {
    gemm_bt<false, true, true, false><<<grid3, blk, 0, stream>>>(
        h2, W3b, b3, zb, kout, nullptr, y,
        p0, p1, p2, p3, cc0, cc1, cc2, cc3, ccur,
        batch, data, hidden, lgx3);
  };

  for (int step = 0; step < 64; ++step) {
    mlp_front(yb);
    stage_k(k1, nullptr, 0.f, nullptr, 0.f, nullptr, 0.f, nullptr, 0.f, hA21);
    mlp_front(zb);
    stage_k(k2, k1, hA31, nullptr, 0.f, nullptr, 0.f, nullptr, 0.f, hA32);
    mlp_front(zb);
    stage_k(k3, k1, hA41, k2, hA42, nullptr, 0.f, nullptr, 0.f, hA43);
    mlp_front(zb);
    stage_k(k4, k1, hA51, k2, hA52, k3, hA53, nullptr, 0.f, hA54);
    mlp_front(zb);
    stage_k(k5, k1, hA61, k2, hA62, k3, hA63, k4, hA64, hA65);
    mlp_front(zb);
    float* yf = (step == 63) ? (float*)d_out : y;
    gemm_bt<false, true, false, true><<<grid3, blk, 0, stream>>>(
        h2, W3b, b3, yb, nullptr, yf, y,
        k1, k3, k4, k5, hB1, hB3, hB4, hB5, hB6,
        batch, data, hidden, lgx3);
  }
}